// Round 13
// baseline (465.969 us; speedup 1.0000x reference)
//
#include <hip/hip_runtime.h>
#include <hip/hip_bf16.h>

#define NCH 256     // H*OUT_DIM = 8*32
#define DIM 256     // IN_DIM
#define BN  64      // nodes per bucket
#define NBMAX 2048  // max buckets (LDS sizing); NB = ceil(N/64) = 1563
#define SEG 8       // NBMAX/256 (bscan, 256 threads)
#define SEG2 2      // NBMAX/1024 (scatter1, 1024 threads)
#define ECHUNK 8192 // edges per scatter block
#define SCAP 4096   // sortb LDS capacity (bucket mean ~1024, std ~32)
#define NPART 64    // stats partial rows

using f32x4  = __attribute__((ext_vector_type(4))) float;
using s16x8  = __attribute__((ext_vector_type(8))) short;
using u16x8  = __attribute__((ext_vector_type(8))) unsigned short;

__device__ __forceinline__ unsigned short f2bf(float x) {
    unsigned u = __float_as_uint(x);
    u += 0x7FFFu + ((u >> 16) & 1u);   // RNE
    return (unsigned short)(u >> 16);
}
__device__ __forceinline__ float bf2f(unsigned short b) {
    return __uint_as_float(((unsigned)b) << 16);
}

// exclusive prefix over the 256 threads' values
__device__ __forceinline__ int block_scan256_excl(int v, int* wtmp) {
    int lane = threadIdx.x & 63, wv = threadIdx.x >> 6;
    int x = v;
#pragma unroll
    for (int d = 1; d < 64; d <<= 1) {
        int t = __shfl_up(x, d);
        if (lane >= d) x += t;
    }
    if (lane == 63) wtmp[wv] = x;
    __syncthreads();
    int wbase = 0;
#pragma unroll
    for (int w = 0; w < 4; ++w) wbase += (w < wv) ? wtmp[w] : 0;
    __syncthreads();
    return wbase + x - v;
}

// exclusive prefix over 1024 threads' values (16 waves)
__device__ __forceinline__ int block_scan1024_excl(int v, int* wtmp) {
    int lane = threadIdx.x & 63, wv = threadIdx.x >> 6;
    int x = v;
#pragma unroll
    for (int d = 1; d < 64; d <<= 1) {
        int t = __shfl_up(x, d);
        if (lane >= d) x += t;
    }
    if (lane == 63) wtmp[wv] = x;
    __syncthreads();
    int wbase = 0;
#pragma unroll
    for (int w = 0; w < 16; ++w) wbase += (w < wv) ? wtmp[w] : 0;
    __syncthreads();
    return wbase + x - v;
}

// ---------- cast W (f32 [256][256]) to bf16 ----------
__global__ __launch_bounds__(256) void cast_w_kernel(const float* __restrict__ W,
                                                     unsigned short* __restrict__ Wb) {
    int i = blockIdx.x * 256 + threadIdx.x;
    Wb[i] = f2bf(W[i]);
}

// ---------- GEMM: z[n][c] = sum_d h[n][d] * W[c][d], z stored bf16 ----------
// 512-thread blocks (8 waves), 128-row tiles, 64KB W-half in LDS.
// R13: software-pipelined A loads (2-buffer rotation at k-half granularity) --
// R12 profile showed 71us at 741 GB/s, VGPR=52: cold loads every tile.
__global__ __launch_bounds__(512, 4) void gemm_z_kernel(const float* __restrict__ h,
                                                        const unsigned short* __restrict__ Wb,
                                                        unsigned short* __restrict__ z,
                                                        int N, int ntiles) {
    __shared__ __align__(16) unsigned short lds[32768];   // 64 KB: 128 cols x 256 k
    int by = blockIdx.y;

    const unsigned short* wsrc = Wb + (size_t)by * 32768;
    for (int it = 0; it < 8; ++it) {
        int c = it * 512 + threadIdx.x;       // 16B chunk index, 4096 total
        int lin = c * 16;
        int dst = lin ^ (((lin >> 9) & 7) << 4);
        *reinterpret_cast<u16x8*>((char*)lds + dst) =
            *reinterpret_cast<const u16x8*>(wsrc + c * 8);
    }
    __syncthreads();   // LDS read-only from here; no barriers in tile loop

    int wv = threadIdx.x >> 6, lane = threadIdx.x & 63;
    int lrow = lane & 15;
    int lk   = (lane >> 4) * 8;

    int ldsoff[8];
#pragma unroll
    for (int kk = 0; kk < 8; ++kk)
        ldsoff[kk] = ((lrow * 512 + kk * 64 + lk * 2) ^ ((lrow & 7) << 4));

    float4 bufA[8], bufB[8];

    // prologue: half0 (kk 0..3) of first tile
    {
        int tile = blockIdx.x;
        int row = tile * 128 + wv * 16 + lrow;
        if (tile < ntiles && row < N) {
            const float* ap = h + (size_t)row * DIM;
#pragma unroll
            for (int kk = 0; kk < 4; ++kk) {
                bufA[2 * kk]     = *reinterpret_cast<const float4*>(ap + kk * 32 + lk);
                bufA[2 * kk + 1] = *reinterpret_cast<const float4*>(ap + kk * 32 + lk + 4);
            }
        } else {
#pragma unroll
            for (int i = 0; i < 8; ++i) bufA[i] = float4{0.f, 0.f, 0.f, 0.f};
        }
    }

    for (int tile = blockIdx.x; tile < ntiles; tile += gridDim.x) {
        int r0  = tile * 128 + wv * 16;
        int row = r0 + lrow;
        bool v  = (row < N);
        const float* ap = h + (size_t)row * DIM;

        // load half1 (kk 4..7) of current tile
        if (v) {
#pragma unroll
            for (int kk = 4; kk < 8; ++kk) {
                bufB[2 * (kk - 4)]     = *reinterpret_cast<const float4*>(ap + kk * 32 + lk);
                bufB[2 * (kk - 4) + 1] = *reinterpret_cast<const float4*>(ap + kk * 32 + lk + 4);
            }
        } else {
#pragma unroll
            for (int i = 0; i < 8; ++i) bufB[i] = float4{0.f, 0.f, 0.f, 0.f};
        }

        f32x4 acc[8];
#pragma unroll
        for (int ct = 0; ct < 8; ++ct) acc[ct] = f32x4{0.f, 0.f, 0.f, 0.f};

        // MFMA on half0 (bufA) while bufB loads are in flight
#pragma unroll
        for (int kk = 0; kk < 4; ++kk) {
            union { s16x8 vv; __hip_bfloat162 b2[4]; } u;
            float4 f0 = bufA[2 * kk], f1 = bufA[2 * kk + 1];
            u.b2[0] = __float22bfloat162_rn(float2{f0.x, f0.y});
            u.b2[1] = __float22bfloat162_rn(float2{f0.z, f0.w});
            u.b2[2] = __float22bfloat162_rn(float2{f1.x, f1.y});
            u.b2[3] = __float22bfloat162_rn(float2{f1.z, f1.w});
            s16x8 a = u.vv;
#pragma unroll
            for (int ct = 0; ct < 8; ++ct) {
                s16x8 b = *reinterpret_cast<const s16x8*>(
                    (const char*)lds + (ldsoff[kk] + ct * 8192));
                acc[ct] = __builtin_amdgcn_mfma_f32_16x16x32_bf16(a, b, acc[ct], 0, 0, 0);
            }
        }

        // bufA consumed: load half0 of NEXT tile into it (in flight under
        // the half1 MFMAs below)
        {
            int ntile = tile + gridDim.x;
            int nrow  = ntile * 128 + wv * 16 + lrow;
            if (ntile < ntiles && nrow < N) {
                const float* nap = h + (size_t)nrow * DIM;
#pragma unroll
                for (int kk = 0; kk < 4; ++kk) {
                    bufA[2 * kk]     = *reinterpret_cast<const float4*>(nap + kk * 32 + lk);
                    bufA[2 * kk + 1] = *reinterpret_cast<const float4*>(nap + kk * 32 + lk + 4);
                }
            } else if (ntile < ntiles) {
#pragma unroll
                for (int i = 0; i < 8; ++i) bufA[i] = float4{0.f, 0.f, 0.f, 0.f};
            }
        }

        // MFMA on half1 (bufB)
#pragma unroll
        for (int kk = 4; kk < 8; ++kk) {
            union { s16x8 vv; __hip_bfloat162 b2[4]; } u;
            float4 f0 = bufB[2 * (kk - 4)], f1 = bufB[2 * (kk - 4) + 1];
            u.b2[0] = __float22bfloat162_rn(float2{f0.x, f0.y});
            u.b2[1] = __float22bfloat162_rn(float2{f0.z, f0.w});
            u.b2[2] = __float22bfloat162_rn(float2{f1.x, f1.y});
            u.b2[3] = __float22bfloat162_rn(float2{f1.z, f1.w});
            s16x8 a = u.vv;
#pragma unroll
            for (int ct = 0; ct < 8; ++ct) {
                s16x8 b = *reinterpret_cast<const s16x8*>(
                    (const char*)lds + (ldsoff[kk] + ct * 8192));
                acc[ct] = __builtin_amdgcn_mfma_f32_16x16x32_bf16(a, b, acc[ct], 0, 0, 0);
            }
        }

        int drow = (lane >> 4) * 4;
#pragma unroll
        for (int ct = 0; ct < 8; ++ct) {
#pragma unroll
            for (int r = 0; r < 4; ++r) {
                int orow = r0 + drow + r;
                if (orow < N)
                    z[(size_t)orow * NCH + by * 128 + ct * 16 + lrow] = f2bf(acc[ct][r]);
            }
        }
    }
}

// ---------- bucket histogram: counts[b] over buckets of 64 dst nodes ----------
__global__ __launch_bounds__(256) void bhist_kernel(const int* __restrict__ dst,
                                                    int* __restrict__ counts, int E, int NB) {
    __shared__ int cnt[NBMAX];
    int tid = threadIdx.x;
    for (int i = tid; i < NB; i += 256) cnt[i] = 0;
    __syncthreads();
    for (int j = blockIdx.x * 256 + tid; j < E; j += gridDim.x * 256)
        atomicAdd(&cnt[dst[j] >> 6], 1);
    __syncthreads();
    for (int i = tid; i < NB; i += 256)
        if (cnt[i]) atomicAdd(&counts[i], cnt[i]);
}

// ---------- scan over NB buckets -> bases[0..NB], cursor copy ----------
__global__ __launch_bounds__(256) void bscan_kernel(const int* __restrict__ counts,
                                                    int* __restrict__ bases,
                                                    int* __restrict__ cursor, int NB) {
    __shared__ int wtmp[4];
    int tid = threadIdx.x;
    int i0 = tid * SEG;
    int tsum = 0;
#pragma unroll
    for (int k = 0; k < SEG; ++k) {
        int idx = i0 + k;
        if (idx < NB) tsum += counts[idx];
    }
    int run = block_scan256_excl(tsum, wtmp);
#pragma unroll
    for (int k = 0; k < SEG; ++k) {
        int idx = i0 + k;
        if (idx < NB) {
            bases[idx]  = run;
            cursor[idx] = run;
            run += counts[idx];
        } else if (idx == NB) {
            bases[NB] = run;
        }
    }
}

// ---------- scatter edges into bucket-grouped packed list ----------
// 1024 threads + sbkt O(1) write-out (R12-proven: 91us -> sub-cutoff).
// pack: src (17b) | local_dst (6b) << 17
__global__ __launch_bounds__(1024) void scatter1_kernel(const int* __restrict__ src,
                                                        const int* __restrict__ dst,
                                                        int* __restrict__ cursor,
                                                        unsigned* __restrict__ pairs,
                                                        int E, int NB) {
    __shared__ int cnt[NBMAX];      // then reused as local cursor
    __shared__ int excl0[NBMAX];
    __shared__ int gb[NBMAX];
    __shared__ unsigned staged[ECHUNK];
    __shared__ unsigned short sbkt[ECHUNK];
    __shared__ int wtmp[16];
    int tid = threadIdx.x;
    int base = blockIdx.x * ECHUNK;
    int n = min(ECHUNK, E - base);

    for (int i = tid; i < NB; i += 1024) cnt[i] = 0;
    __syncthreads();
    for (int j = tid; j < n; j += 1024)
        atomicAdd(&cnt[dst[base + j] >> 6], 1);
    __syncthreads();

    int i0 = tid * SEG2;
    int tsum = 0;
#pragma unroll
    for (int k = 0; k < SEG2; ++k) {
        int idx = i0 + k;
        if (idx < NB) tsum += cnt[idx];
    }
    int run = block_scan1024_excl(tsum, wtmp);
#pragma unroll
    for (int k = 0; k < SEG2; ++k) {
        int idx = i0 + k;
        if (idx < NB) {
            int c = cnt[idx];
            excl0[idx] = run;
            gb[idx] = c ? atomicAdd(&cursor[idx], c) : 0;
            run += c;
        }
    }
    __syncthreads();
    for (int i = tid; i < NB; i += 1024) cnt[i] = excl0[i];   // cnt -> local cursor
    __syncthreads();
    for (int j = tid; j < n; j += 1024) {
        int d = dst[base + j];
        int b = d >> 6;
        int slot = atomicAdd(&cnt[b], 1);
        staged[slot] = (unsigned)src[base + j] | ((unsigned)(d & 63) << 17);
        sbkt[slot]   = (unsigned short)b;
    }
    __syncthreads();
    // linear write-out: consecutive j -> consecutive positions within bucket runs
    for (int j = tid; j < n; j += 1024) {
        int b = sbkt[j];
        pairs[gb[b] + (j - excl0[b])] = staged[j];
    }
}

// ---------- in-bucket counting sort + per-node rowptr; pairs -> plain src ----------
__global__ __launch_bounds__(256) void sortb_kernel(unsigned* __restrict__ pairs,
                                                    const int* __restrict__ bases,
                                                    int* __restrict__ rowptr,
                                                    int N, int NB, int E) {
    __shared__ unsigned raw[SCAP];
    __shared__ unsigned srt[SCAP];
    __shared__ int cnt[BN];
    __shared__ int rp[BN + 1];
    __shared__ int cur[BN];
    int bkt = blockIdx.x, tid = threadIdx.x;
    int ebeg = bases[bkt];
    int ne = min(bases[bkt + 1] - ebeg, SCAP);

    if (tid < BN) cnt[tid] = 0;
    __syncthreads();
    for (int i = tid; i < ne; i += 256) {
        unsigned e = pairs[ebeg + i];
        raw[i] = e;
        atomicAdd(&cnt[(e >> 17) & 63], 1);
    }
    __syncthreads();
    if (tid < 64) {                 // wave 0: exclusive scan of cnt[0..63]
        int x = cnt[tid];
#pragma unroll
        for (int d = 1; d < 64; d <<= 1) {
            int t = __shfl_up(x, d);
            if (tid >= d) x += t;
        }
        rp[tid + 1] = x;
        if (tid == 0) rp[0] = 0;
    }
    __syncthreads();
    if (tid < BN) cur[tid] = rp[tid];
    int node = bkt * BN + tid;
    if (tid < BN && node < N) rowptr[node] = ebeg + rp[tid];
    if (bkt == NB - 1 && tid == 0) rowptr[N] = E;
    __syncthreads();
    for (int i = tid; i < ne; i += 256) {
        unsigned e = raw[i];
        int slot = atomicAdd(&cur[(e >> 17) & 63], 1);
        srt[slot] = e & 0x1FFFFu;
    }
    __syncthreads();
    for (int i = tid; i < ne; i += 256) pairs[ebeg + i] = srt[i];
}

// ---------- pull aggregation + register-level BN stats ----------
// 4 nodes per wave (16 per block); 32 lanes per row (16B/lane), 2 edges per
// pair-step, unroll 4 -> 4 outstanding 16B gathers per lane (proven best).
// Single dispatch again (R12: the diagnostic 2-way split cost ~18us).
template <int BF16OUT>
__global__ __launch_bounds__(256) void agg_kernel(const unsigned short* __restrict__ z,
                                                  const unsigned* __restrict__ pairs,
                                                  const int* __restrict__ rowptr,
                                                  float* __restrict__ outf,
                                                  unsigned short* __restrict__ outb,
                                                  float* __restrict__ partials,
                                                  int node0, int N) {
    __shared__ float redu[4][32][17];   // 17: odd stride -> conflict-free
    int tid = threadIdx.x;
    int wv = tid >> 6, lane = tid & 63;
    int half = lane >> 5;          // which edge within the pair
    int l    = lane & 31;          // channel group: owns channels 8l..8l+7
    const unsigned short* zb = z + l * 8;

    float sum[8], sq[8];
#pragma unroll
    for (int j = 0; j < 8; ++j) { sum[j] = 0.f; sq[j] = 0.f; }

    for (int k = 0; k < 4; ++k) {
        int node = node0 + blockIdx.x * 16 + wv * 4 + k;
        if (node >= N) break;
        int beg = rowptr[node], end = rowptr[node + 1];

        float s[8];
#pragma unroll
        for (int j = 0; j < 8; ++j) s[j] = 0.f;

        int i = beg + half;
        for (; i + 6 < end; i += 8) {
            int n0 = pairs[i];
            int n1 = pairs[i + 2];
            int n2 = pairs[i + 4];
            int n3 = pairs[i + 6];
            u16x8 v0 = *reinterpret_cast<const u16x8*>(zb + (size_t)n0 * NCH);
            u16x8 v1 = *reinterpret_cast<const u16x8*>(zb + (size_t)n1 * NCH);
            u16x8 v2 = *reinterpret_cast<const u16x8*>(zb + (size_t)n2 * NCH);
            u16x8 v3 = *reinterpret_cast<const u16x8*>(zb + (size_t)n3 * NCH);
#pragma unroll
            for (int j = 0; j < 8; ++j)
                s[j] += (bf2f(v0[j]) + bf2f(v1[j])) + (bf2f(v2[j]) + bf2f(v3[j]));
        }
        for (; i < end; i += 2) {
            int n0 = pairs[i];
            u16x8 v0 = *reinterpret_cast<const u16x8*>(zb + (size_t)n0 * NCH);
#pragma unroll
            for (int j = 0; j < 8; ++j) s[j] += bf2f(v0[j]);
        }
#pragma unroll
        for (int j = 0; j < 8; ++j) s[j] += __shfl_xor(s[j], 32);

        if (half == 0) {
            if (BF16OUT) {
                u16x8 ob;
#pragma unroll
                for (int j = 0; j < 8; ++j) ob[j] = f2bf(s[j]);
                *reinterpret_cast<u16x8*>(outb + (size_t)node * NCH + l * 8) = ob;
            } else {
                float4 o0; o0.x = s[0]; o0.y = s[1]; o0.z = s[2]; o0.w = s[3];
                float4 o1; o1.x = s[4]; o1.y = s[5]; o1.z = s[6]; o1.w = s[7];
                float* p = outf + (size_t)node * NCH + l * 8;
                *reinterpret_cast<float4*>(p)     = o0;
                *reinterpret_cast<float4*>(p + 4) = o1;
            }
#pragma unroll
            for (int j = 0; j < 8; ++j) { sum[j] += s[j]; sq[j] += s[j] * s[j]; }
        }
    }

    if (half == 0) {
#pragma unroll
        for (int j = 0; j < 8; ++j) {
            redu[wv][l][j]     = sum[j];
            redu[wv][l][j + 8] = sq[j];
        }
    }
    __syncthreads();
    {
        int c = tid;                 // channel 0..255
        int lc = c >> 3, jc = c & 7;
        float v = 0.f, q = 0.f;
#pragma unroll
        for (int w = 0; w < 4; ++w) {
            v += redu[w][lc][jc];
            q += redu[w][lc][jc + 8];
        }
        float* prow = partials + (size_t)(blockIdx.x & (NPART - 1)) * 512;
        atomicAdd(&prow[c], v);
        atomicAdd(&prow[256 + c], q);
    }
}

// ---------- finalize scale/shift from partials ----------
__global__ __launch_bounds__(256) void fscale_kernel(const float* __restrict__ partials,
                                                     const float* __restrict__ gamma,
                                                     const float* __restrict__ beta,
                                                     float* __restrict__ ss, float invN) {
    int c = threadIdx.x;
    float sum = 0.f, sq = 0.f;
    for (int r = 0; r < NPART; ++r) {
        sum += partials[(size_t)r * 512 + c];
        sq  += partials[(size_t)r * 512 + 256 + c];
    }
    float mean = sum * invN;
    float var  = sq * invN - mean * mean;
    float rs   = rsqrtf(var + 1e-5f);
    float sc   = gamma[c] * rs;
    ss[c]       = sc;
    ss[256 + c] = beta[c] - mean * sc;
}

// ---------- final: out = h + elu(agg*scale + shift) ----------
// scale/shift hoisted to registers; native exp2 ELU (R11-proven: 105->~35us).
template <int BF16IN>
__global__ __launch_bounds__(256) void final_kernel(const float* __restrict__ h,
                                                    const float* __restrict__ ss,
                                                    const float* __restrict__ aggf,
                                                    const unsigned short* __restrict__ aggb,
                                                    float* __restrict__ out, int total8) {
    int tid0 = blockIdx.x * 256 + threadIdx.x;
    int stride = gridDim.x * 256;         // multiple of 32 -> (i & 31) invariant
    int cb = (tid0 & 31) * 8;
    float sc[8], sh[8];
#pragma unroll
    for (int j = 0; j < 8; ++j) {
        sc[j] = ss[cb + j];
        sh[j] = ss[256 + cb + j];
    }
    const float LOG2E = 1.44269504088896f;
    for (int i = tid0; i < total8; i += stride) {
        float a[8];
        if (BF16IN) {
            u16x8 v = *reinterpret_cast<const u16x8*>(aggb + (size_t)i * 8);
#pragma unroll
            for (int j = 0; j < 8; ++j) a[j] = bf2f(v[j]);
        } else {
            float4 x = *reinterpret_cast<const float4*>(aggf + (size_t)i * 8);
            float4 y = *reinterpret_cast<const float4*>(aggf + (size_t)i * 8 + 4);
            a[0] = x.x; a[1] = x.y; a[2] = x.z; a[3] = x.w;
            a[4] = y.x; a[5] = y.y; a[6] = y.z; a[7] = y.w;
        }
        float4 h0 = *reinterpret_cast<const float4*>(h + (size_t)i * 8);
        float4 h1 = *reinterpret_cast<const float4*>(h + (size_t)i * 8 + 4);
        float r[8];
#pragma unroll
        for (int j = 0; j < 8; ++j) {
            float y = a[j] * sc[j] + sh[j];
            float e = __builtin_amdgcn_exp2f(y * LOG2E) - 1.0f;
            r[j] = (y > 0.f) ? y : e;
        }
        float4 o0, o1;
        o0.x = h0.x + r[0]; o0.y = h0.y + r[1]; o0.z = h0.z + r[2]; o0.w = h0.w + r[3];
        o1.x = h1.x + r[4]; o1.y = h1.y + r[5]; o1.z = h1.z + r[6]; o1.w = h1.w + r[7];
        *reinterpret_cast<float4*>(out + (size_t)i * 8)     = o0;
        *reinterpret_cast<float4*>(out + (size_t)i * 8 + 4) = o1;
    }
}

extern "C" void kernel_launch(void* const* d_in, const int* in_sizes, int n_in,
                              void* d_out, int out_size, void* d_ws, size_t ws_size,
                              hipStream_t stream) {
    const float* h     = (const float*)d_in[0];
    const float* W     = (const float*)d_in[1];
    const float* gamma = (const float*)d_in[2];
    const float* beta  = (const float*)d_in[3];
    const int*   src   = (const int*)d_in[4];
    const int*   dst   = (const int*)d_in[5];
    int N = in_sizes[0] / DIM;   // 100000
    int E = in_sizes[4];         // 1600000
    int NB = (N + BN - 1) / BN;  // 1563
    float* out = (float*)d_out;

    char* ws = (char*)d_ws;
    size_t off = 0;
    auto alloc = [&](size_t bytes) {
        size_t o = off;
        off += (bytes + 255) & ~(size_t)255;
        return o;
    };
    unsigned short* z        = (unsigned short*)(ws + alloc((size_t)N * NCH * 2));
    unsigned short* Wb       = (unsigned short*)(ws + alloc((size_t)NCH * DIM * 2));
    size_t zero_begin        = off;
    int*            counts   = (int*)(ws + alloc((size_t)NB * 4));
    float*          partials = (float*)(ws + alloc((size_t)NPART * 512 * 4));
    size_t zero_end          = off;
    int*            cursor   = (int*)(ws + alloc((size_t)NB * 4));
    int*            bases    = (int*)(ws + alloc((size_t)(NB + 1) * 4));
    int*            rowptr   = (int*)(ws + alloc((size_t)(N + 1) * 4));
    float*          ss       = (float*)(ws + alloc(512 * 4));
    unsigned*       pairs    = (unsigned*)(ws + alloc((size_t)E * 4));
    // optional bf16 agg buffer (51 MB) -- only if workspace allows
    size_t aggb_off          = alloc((size_t)N * NCH * 2);
    bool bf16agg = (off <= ws_size);
    unsigned short* aggb     = (unsigned short*)(ws + aggb_off);

    hipMemsetAsync(ws + zero_begin, 0, zero_end - zero_begin, stream);

    cast_w_kernel<<<(NCH * DIM) / 256, 256, 0, stream>>>(W, Wb);

    int ntiles = (N + 127) / 128;               // 782
    int gx = (ntiles + 3) / 4;                  // 196 -> 392 blocks, 2/CU, one round
    gemm_z_kernel<<<dim3(gx, 2), 512, 0, stream>>>(h, Wb, z, N, ntiles);

    bhist_kernel<<<256, 256, 0, stream>>>(dst, counts, E, NB);
    bscan_kernel<<<1, 256, 0, stream>>>(counts, bases, cursor, NB);
    scatter1_kernel<<<(E + ECHUNK - 1) / ECHUNK, 1024, 0, stream>>>(src, dst, cursor, pairs, E, NB);
    sortb_kernel<<<NB, 256, 0, stream>>>(pairs, bases, rowptr, N, NB, E);

    int nblk = (N + 15) / 16;                   // 6250
    if (bf16agg)
        agg_kernel<1><<<nblk, 256, 0, stream>>>(z, pairs, rowptr, out, aggb, partials, 0, N);
    else
        agg_kernel<0><<<nblk, 256, 0, stream>>>(z, pairs, rowptr, out, aggb, partials, 0, N);

    fscale_kernel<<<1, 256, 0, stream>>>(partials, gamma, beta, ss, 1.0f / (float)N);
    int total8 = N * (NCH / 8);
    if (bf16agg)
        final_kernel<1><<<2048, 256, 0, stream>>>(h, ss, out, aggb, out, total8);
    else
        final_kernel<0><<<2048, 256, 0, stream>>>(h, ss, out, aggb, out, total8);
}

// Round 14
// 282.092 us; speedup vs baseline: 1.6518x; 1.6518x over previous
//
#include <hip/hip_runtime.h>
#include <hip/hip_bf16.h>

#define NCH 256     // H*OUT_DIM = 8*32
#define DIM 256     // IN_DIM
#define BN  64      // nodes per bucket
#define NBMAX 2048  // max buckets (LDS sizing); NB = ceil(N/64) = 1563
#define SEG 8       // NBMAX/256 (bscan, 256 threads)
#define SEG2 2      // NBMAX/1024 (scatter1, 1024 threads)
#define ECHUNK 8192 // edges per scatter block
#define SCAP 4096   // sortb LDS capacity (bucket mean ~1024, std ~32)
#define NPART 64    // stats partial rows

using f32x4  = __attribute__((ext_vector_type(4))) float;
using s16x8  = __attribute__((ext_vector_type(8))) short;
using u16x8  = __attribute__((ext_vector_type(8))) unsigned short;

__device__ __forceinline__ unsigned short f2bf(float x) {
    unsigned u = __float_as_uint(x);
    u += 0x7FFFu + ((u >> 16) & 1u);   // RNE
    return (unsigned short)(u >> 16);
}
__device__ __forceinline__ float bf2f(unsigned short b) {
    return __uint_as_float(((unsigned)b) << 16);
}

// exclusive prefix over the 256 threads' values
__device__ __forceinline__ int block_scan256_excl(int v, int* wtmp) {
    int lane = threadIdx.x & 63, wv = threadIdx.x >> 6;
    int x = v;
#pragma unroll
    for (int d = 1; d < 64; d <<= 1) {
        int t = __shfl_up(x, d);
        if (lane >= d) x += t;
    }
    if (lane == 63) wtmp[wv] = x;
    __syncthreads();
    int wbase = 0;
#pragma unroll
    for (int w = 0; w < 4; ++w) wbase += (w < wv) ? wtmp[w] : 0;
    __syncthreads();
    return wbase + x - v;
}

// exclusive prefix over 1024 threads' values (16 waves)
__device__ __forceinline__ int block_scan1024_excl(int v, int* wtmp) {
    int lane = threadIdx.x & 63, wv = threadIdx.x >> 6;
    int x = v;
#pragma unroll
    for (int d = 1; d < 64; d <<= 1) {
        int t = __shfl_up(x, d);
        if (lane >= d) x += t;
    }
    if (lane == 63) wtmp[wv] = x;
    __syncthreads();
    int wbase = 0;
#pragma unroll
    for (int w = 0; w < 16; ++w) wbase += (w < wv) ? wtmp[w] : 0;
    __syncthreads();
    return wbase + x - v;
}

// ---------- cast W (f32 [256][256]) to bf16 ----------
__global__ __launch_bounds__(256) void cast_w_kernel(const float* __restrict__ W,
                                                     unsigned short* __restrict__ Wb) {
    int i = blockIdx.x * 256 + threadIdx.x;
    Wb[i] = f2bf(W[i]);
}

// ---------- GEMM: z[n][c] = sum_d h[n][d] * W[c][d], z stored bf16 ----------
// 512-thread blocks (8 waves), 128-row tiles, 64KB W-half in LDS.
// R12-proven version (71us). R13's reg-level software pipeline SPILLED
// (bufA+bufB live across MFMA chains -> scratch, 269us) -- do not reintroduce.
__global__ __launch_bounds__(512, 4) void gemm_z_kernel(const float* __restrict__ h,
                                                        const unsigned short* __restrict__ Wb,
                                                        unsigned short* __restrict__ z,
                                                        int N, int ntiles) {
    __shared__ __align__(16) unsigned short lds[32768];   // 64 KB: 128 cols x 256 k
    int by = blockIdx.y;

    const unsigned short* wsrc = Wb + (size_t)by * 32768;
    for (int it = 0; it < 8; ++it) {
        int c = it * 512 + threadIdx.x;       // 16B chunk index, 4096 total
        int lin = c * 16;
        int dst = lin ^ (((lin >> 9) & 7) << 4);
        *reinterpret_cast<u16x8*>((char*)lds + dst) =
            *reinterpret_cast<const u16x8*>(wsrc + c * 8);
    }
    __syncthreads();   // LDS read-only from here; no barriers in tile loop

    int wv = threadIdx.x >> 6, lane = threadIdx.x & 63;
    int lrow = lane & 15;
    int lk   = (lane >> 4) * 8;

    int ldsoff[8];
#pragma unroll
    for (int kk = 0; kk < 8; ++kk)
        ldsoff[kk] = ((lrow * 512 + kk * 64 + lk * 2) ^ ((lrow & 7) << 4));

    for (int tile = blockIdx.x; tile < ntiles; tile += gridDim.x) {
        int r0 = tile * 128 + wv * 16;
        if (r0 >= N) continue;
        int row = r0 + lrow;

        float4 cur[16];
        if (row < N) {
            const float* ap = h + (size_t)row * DIM;
#pragma unroll
            for (int kk = 0; kk < 8; ++kk) {
                cur[2 * kk]     = *reinterpret_cast<const float4*>(ap + kk * 32 + lk);
                cur[2 * kk + 1] = *reinterpret_cast<const float4*>(ap + kk * 32 + lk + 4);
            }
        } else {
#pragma unroll
            for (int i = 0; i < 16; ++i) cur[i] = float4{0.f, 0.f, 0.f, 0.f};
        }

        f32x4 acc[8];
#pragma unroll
        for (int ct = 0; ct < 8; ++ct) acc[ct] = f32x4{0.f, 0.f, 0.f, 0.f};
#pragma unroll
        for (int kk = 0; kk < 8; ++kk) {
            union { s16x8 v; __hip_bfloat162 b2[4]; } u;
            float4 f0 = cur[2 * kk], f1 = cur[2 * kk + 1];
            u.b2[0] = __float22bfloat162_rn(float2{f0.x, f0.y});
            u.b2[1] = __float22bfloat162_rn(float2{f0.z, f0.w});
            u.b2[2] = __float22bfloat162_rn(float2{f1.x, f1.y});
            u.b2[3] = __float22bfloat162_rn(float2{f1.z, f1.w});
            s16x8 a = u.v;
#pragma unroll
            for (int ct = 0; ct < 8; ++ct) {
                s16x8 b = *reinterpret_cast<const s16x8*>(
                    (const char*)lds + (ldsoff[kk] + ct * 8192));
                acc[ct] = __builtin_amdgcn_mfma_f32_16x16x32_bf16(a, b, acc[ct], 0, 0, 0);
            }
        }
        int drow = (lane >> 4) * 4;
#pragma unroll
        for (int ct = 0; ct < 8; ++ct) {
#pragma unroll
            for (int r = 0; r < 4; ++r) {
                int orow = r0 + drow + r;
                if (orow < N)
                    z[(size_t)orow * NCH + by * 128 + ct * 16 + lrow] = f2bf(acc[ct][r]);
            }
        }
    }
}

// ---------- bucket histogram: counts[b] over buckets of 64 dst nodes ----------
__global__ __launch_bounds__(256) void bhist_kernel(const int* __restrict__ dst,
                                                    int* __restrict__ counts, int E, int NB) {
    __shared__ int cnt[NBMAX];
    int tid = threadIdx.x;
    for (int i = tid; i < NB; i += 256) cnt[i] = 0;
    __syncthreads();
    for (int j = blockIdx.x * 256 + tid; j < E; j += gridDim.x * 256)
        atomicAdd(&cnt[dst[j] >> 6], 1);
    __syncthreads();
    for (int i = tid; i < NB; i += 256)
        if (cnt[i]) atomicAdd(&counts[i], cnt[i]);
}

// ---------- scan over NB buckets -> bases[0..NB], cursor copy ----------
__global__ __launch_bounds__(256) void bscan_kernel(const int* __restrict__ counts,
                                                    int* __restrict__ bases,
                                                    int* __restrict__ cursor, int NB) {
    __shared__ int wtmp[4];
    int tid = threadIdx.x;
    int i0 = tid * SEG;
    int tsum = 0;
#pragma unroll
    for (int k = 0; k < SEG; ++k) {
        int idx = i0 + k;
        if (idx < NB) tsum += counts[idx];
    }
    int run = block_scan256_excl(tsum, wtmp);
#pragma unroll
    for (int k = 0; k < SEG; ++k) {
        int idx = i0 + k;
        if (idx < NB) {
            bases[idx]  = run;
            cursor[idx] = run;
            run += counts[idx];
        } else if (idx == NB) {
            bases[NB] = run;
        }
    }
}

// ---------- scatter edges into bucket-grouped packed list ----------
// 1024 threads + sbkt O(1) write-out (R12-proven: 91us -> sub-cutoff).
// pack: src (17b) | local_dst (6b) << 17
__global__ __launch_bounds__(1024) void scatter1_kernel(const int* __restrict__ src,
                                                        const int* __restrict__ dst,
                                                        int* __restrict__ cursor,
                                                        unsigned* __restrict__ pairs,
                                                        int E, int NB) {
    __shared__ int cnt[NBMAX];      // then reused as local cursor
    __shared__ int excl0[NBMAX];
    __shared__ int gb[NBMAX];
    __shared__ unsigned staged[ECHUNK];
    __shared__ unsigned short sbkt[ECHUNK];
    __shared__ int wtmp[16];
    int tid = threadIdx.x;
    int base = blockIdx.x * ECHUNK;
    int n = min(ECHUNK, E - base);

    for (int i = tid; i < NB; i += 1024) cnt[i] = 0;
    __syncthreads();
    for (int j = tid; j < n; j += 1024)
        atomicAdd(&cnt[dst[base + j] >> 6], 1);
    __syncthreads();

    int i0 = tid * SEG2;
    int tsum = 0;
#pragma unroll
    for (int k = 0; k < SEG2; ++k) {
        int idx = i0 + k;
        if (idx < NB) tsum += cnt[idx];
    }
    int run = block_scan1024_excl(tsum, wtmp);
#pragma unroll
    for (int k = 0; k < SEG2; ++k) {
        int idx = i0 + k;
        if (idx < NB) {
            int c = cnt[idx];
            excl0[idx] = run;
            gb[idx] = c ? atomicAdd(&cursor[idx], c) : 0;
            run += c;
        }
    }
    __syncthreads();
    for (int i = tid; i < NB; i += 1024) cnt[i] = excl0[i];   // cnt -> local cursor
    __syncthreads();
    for (int j = tid; j < n; j += 1024) {
        int d = dst[base + j];
        int b = d >> 6;
        int slot = atomicAdd(&cnt[b], 1);
        staged[slot] = (unsigned)src[base + j] | ((unsigned)(d & 63) << 17);
        sbkt[slot]   = (unsigned short)b;
    }
    __syncthreads();
    // linear write-out: consecutive j -> consecutive positions within bucket runs
    for (int j = tid; j < n; j += 1024) {
        int b = sbkt[j];
        pairs[gb[b] + (j - excl0[b])] = staged[j];
    }
}

// ---------- in-bucket counting sort + per-node rowptr; pairs -> plain src ----------
__global__ __launch_bounds__(256) void sortb_kernel(unsigned* __restrict__ pairs,
                                                    const int* __restrict__ bases,
                                                    int* __restrict__ rowptr,
                                                    int N, int NB, int E) {
    __shared__ unsigned raw[SCAP];
    __shared__ unsigned srt[SCAP];
    __shared__ int cnt[BN];
    __shared__ int rp[BN + 1];
    __shared__ int cur[BN];
    int bkt = blockIdx.x, tid = threadIdx.x;
    int ebeg = bases[bkt];
    int ne = min(bases[bkt + 1] - ebeg, SCAP);

    if (tid < BN) cnt[tid] = 0;
    __syncthreads();
    for (int i = tid; i < ne; i += 256) {
        unsigned e = pairs[ebeg + i];
        raw[i] = e;
        atomicAdd(&cnt[(e >> 17) & 63], 1);
    }
    __syncthreads();
    if (tid < 64) {                 // wave 0: exclusive scan of cnt[0..63]
        int x = cnt[tid];
#pragma unroll
        for (int d = 1; d < 64; d <<= 1) {
            int t = __shfl_up(x, d);
            if (tid >= d) x += t;
        }
        rp[tid + 1] = x;
        if (tid == 0) rp[0] = 0;
    }
    __syncthreads();
    if (tid < BN) cur[tid] = rp[tid];
    int node = bkt * BN + tid;
    if (tid < BN && node < N) rowptr[node] = ebeg + rp[tid];
    if (bkt == NB - 1 && tid == 0) rowptr[N] = E;
    __syncthreads();
    for (int i = tid; i < ne; i += 256) {
        unsigned e = raw[i];
        int slot = atomicAdd(&cur[(e >> 17) & 63], 1);
        srt[slot] = e & 0x1FFFFu;
    }
    __syncthreads();
    for (int i = tid; i < ne; i += 256) pairs[ebeg + i] = srt[i];
}

// ---------- pull aggregation + register-level BN stats ----------
// 4 nodes per wave (16 per block); 32 lanes per row (16B/lane), 2 edges per
// pair-step, unroll 4 -> 4 outstanding 16B gathers per lane (proven best).
template <int BF16OUT>
__global__ __launch_bounds__(256) void agg_kernel(const unsigned short* __restrict__ z,
                                                  const unsigned* __restrict__ pairs,
                                                  const int* __restrict__ rowptr,
                                                  float* __restrict__ outf,
                                                  unsigned short* __restrict__ outb,
                                                  float* __restrict__ partials,
                                                  int node0, int N) {
    __shared__ float redu[4][32][17];   // 17: odd stride -> conflict-free
    int tid = threadIdx.x;
    int wv = tid >> 6, lane = tid & 63;
    int half = lane >> 5;          // which edge within the pair
    int l    = lane & 31;          // channel group: owns channels 8l..8l+7
    const unsigned short* zb = z + l * 8;

    float sum[8], sq[8];
#pragma unroll
    for (int j = 0; j < 8; ++j) { sum[j] = 0.f; sq[j] = 0.f; }

    for (int k = 0; k < 4; ++k) {
        int node = node0 + blockIdx.x * 16 + wv * 4 + k;
        if (node >= N) break;
        int beg = rowptr[node], end = rowptr[node + 1];

        float s[8];
#pragma unroll
        for (int j = 0; j < 8; ++j) s[j] = 0.f;

        int i = beg + half;
        for (; i + 6 < end; i += 8) {
            int n0 = pairs[i];
            int n1 = pairs[i + 2];
            int n2 = pairs[i + 4];
            int n3 = pairs[i + 6];
            u16x8 v0 = *reinterpret_cast<const u16x8*>(zb + (size_t)n0 * NCH);
            u16x8 v1 = *reinterpret_cast<const u16x8*>(zb + (size_t)n1 * NCH);
            u16x8 v2 = *reinterpret_cast<const u16x8*>(zb + (size_t)n2 * NCH);
            u16x8 v3 = *reinterpret_cast<const u16x8*>(zb + (size_t)n3 * NCH);
#pragma unroll
            for (int j = 0; j < 8; ++j)
                s[j] += (bf2f(v0[j]) + bf2f(v1[j])) + (bf2f(v2[j]) + bf2f(v3[j]));
        }
        for (; i < end; i += 2) {
            int n0 = pairs[i];
            u16x8 v0 = *reinterpret_cast<const u16x8*>(zb + (size_t)n0 * NCH);
#pragma unroll
            for (int j = 0; j < 8; ++j) s[j] += bf2f(v0[j]);
        }
#pragma unroll
        for (int j = 0; j < 8; ++j) s[j] += __shfl_xor(s[j], 32);

        if (half == 0) {
            if (BF16OUT) {
                u16x8 ob;
#pragma unroll
                for (int j = 0; j < 8; ++j) ob[j] = f2bf(s[j]);
                *reinterpret_cast<u16x8*>(outb + (size_t)node * NCH + l * 8) = ob;
            } else {
                float4 o0; o0.x = s[0]; o0.y = s[1]; o0.z = s[2]; o0.w = s[3];
                float4 o1; o1.x = s[4]; o1.y = s[5]; o1.z = s[6]; o1.w = s[7];
                float* p = outf + (size_t)node * NCH + l * 8;
                *reinterpret_cast<float4*>(p)     = o0;
                *reinterpret_cast<float4*>(p + 4) = o1;
            }
#pragma unroll
            for (int j = 0; j < 8; ++j) { sum[j] += s[j]; sq[j] += s[j] * s[j]; }
        }
    }

    if (half == 0) {
#pragma unroll
        for (int j = 0; j < 8; ++j) {
            redu[wv][l][j]     = sum[j];
            redu[wv][l][j + 8] = sq[j];
        }
    }
    __syncthreads();
    {
        int c = tid;                 // channel 0..255
        int lc = c >> 3, jc = c & 7;
        float v = 0.f, q = 0.f;
#pragma unroll
        for (int w = 0; w < 4; ++w) {
            v += redu[w][lc][jc];
            q += redu[w][lc][jc + 8];
        }
        float* prow = partials + (size_t)(blockIdx.x & (NPART - 1)) * 512;
        atomicAdd(&prow[c], v);
        atomicAdd(&prow[256 + c], q);
    }
}

// ---------- finalize scale/shift from partials ----------
__global__ __launch_bounds__(256) void fscale_kernel(const float* __restrict__ partials,
                                                     const float* __restrict__ gamma,
                                                     const float* __restrict__ beta,
                                                     float* __restrict__ ss, float invN) {
    int c = threadIdx.x;
    float sum = 0.f, sq = 0.f;
    for (int r = 0; r < NPART; ++r) {
        sum += partials[(size_t)r * 512 + c];
        sq  += partials[(size_t)r * 512 + 256 + c];
    }
    float mean = sum * invN;
    float var  = sq * invN - mean * mean;
    float rs   = rsqrtf(var + 1e-5f);
    float sc   = gamma[c] * rs;
    ss[c]       = sc;
    ss[256 + c] = beta[c] - mean * sc;
}

// ---------- final: out = h + elu(agg*scale + shift) ----------
// scale/shift hoisted to registers; native exp2 ELU (R11-proven: 105->~35us).
template <int BF16IN>
__global__ __launch_bounds__(256) void final_kernel(const float* __restrict__ h,
                                                    const float* __restrict__ ss,
                                                    const float* __restrict__ aggf,
                                                    const unsigned short* __restrict__ aggb,
                                                    float* __restrict__ out, int total8) {
    int tid0 = blockIdx.x * 256 + threadIdx.x;
    int stride = gridDim.x * 256;         // multiple of 32 -> (i & 31) invariant
    int cb = (tid0 & 31) * 8;
    float sc[8], sh[8];
#pragma unroll
    for (int j = 0; j < 8; ++j) {
        sc[j] = ss[cb + j];
        sh[j] = ss[256 + cb + j];
    }
    const float LOG2E = 1.44269504088896f;
    for (int i = tid0; i < total8; i += stride) {
        float a[8];
        if (BF16IN) {
            u16x8 v = *reinterpret_cast<const u16x8*>(aggb + (size_t)i * 8);
#pragma unroll
            for (int j = 0; j < 8; ++j) a[j] = bf2f(v[j]);
        } else {
            float4 x = *reinterpret_cast<const float4*>(aggf + (size_t)i * 8);
            float4 y = *reinterpret_cast<const float4*>(aggf + (size_t)i * 8 + 4);
            a[0] = x.x; a[1] = x.y; a[2] = x.z; a[3] = x.w;
            a[4] = y.x; a[5] = y.y; a[6] = y.z; a[7] = y.w;
        }
        float4 h0 = *reinterpret_cast<const float4*>(h + (size_t)i * 8);
        float4 h1 = *reinterpret_cast<const float4*>(h + (size_t)i * 8 + 4);
        float r[8];
#pragma unroll
        for (int j = 0; j < 8; ++j) {
            float y = a[j] * sc[j] + sh[j];
            float e = __builtin_amdgcn_exp2f(y * LOG2E) - 1.0f;
            r[j] = (y > 0.f) ? y : e;
        }
        float4 o0, o1;
        o0.x = h0.x + r[0]; o0.y = h0.y + r[1]; o0.z = h0.z + r[2]; o0.w = h0.w + r[3];
        o1.x = h1.x + r[4]; o1.y = h1.y + r[5]; o1.z = h1.z + r[6]; o1.w = h1.w + r[7];
        *reinterpret_cast<float4*>(out + (size_t)i * 8)     = o0;
        *reinterpret_cast<float4*>(out + (size_t)i * 8 + 4) = o1;
    }
}

extern "C" void kernel_launch(void* const* d_in, const int* in_sizes, int n_in,
                              void* d_out, int out_size, void* d_ws, size_t ws_size,
                              hipStream_t stream) {
    const float* h     = (const float*)d_in[0];
    const float* W     = (const float*)d_in[1];
    const float* gamma = (const float*)d_in[2];
    const float* beta  = (const float*)d_in[3];
    const int*   src   = (const int*)d_in[4];
    const int*   dst   = (const int*)d_in[5];
    int N = in_sizes[0] / DIM;   // 100000
    int E = in_sizes[4];         // 1600000
    int NB = (N + BN - 1) / BN;  // 1563
    float* out = (float*)d_out;

    char* ws = (char*)d_ws;
    size_t off = 0;
    auto alloc = [&](size_t bytes) {
        size_t o = off;
        off += (bytes + 255) & ~(size_t)255;
        return o;
    };
    unsigned short* z        = (unsigned short*)(ws + alloc((size_t)N * NCH * 2));
    unsigned short* Wb       = (unsigned short*)(ws + alloc((size_t)NCH * DIM * 2));
    size_t zero_begin        = off;
    int*            counts   = (int*)(ws + alloc((size_t)NB * 4));
    float*          partials = (float*)(ws + alloc((size_t)NPART * 512 * 4));
    size_t zero_end          = off;
    int*            cursor   = (int*)(ws + alloc((size_t)NB * 4));
    int*            bases    = (int*)(ws + alloc((size_t)(NB + 1) * 4));
    int*            rowptr   = (int*)(ws + alloc((size_t)(N + 1) * 4));
    float*          ss       = (float*)(ws + alloc(512 * 4));
    unsigned*       pairs    = (unsigned*)(ws + alloc((size_t)E * 4));
    // optional bf16 agg buffer (51 MB) -- only if workspace allows
    size_t aggb_off          = alloc((size_t)N * NCH * 2);
    bool bf16agg = (off <= ws_size);
    unsigned short* aggb     = (unsigned short*)(ws + aggb_off);

    hipMemsetAsync(ws + zero_begin, 0, zero_end - zero_begin, stream);

    cast_w_kernel<<<(NCH * DIM) / 256, 256, 0, stream>>>(W, Wb);

    int ntiles = (N + 127) / 128;               // 782
    int gx = (ntiles + 3) / 4;                  // 196 -> 392 blocks, 2/CU, one round
    gemm_z_kernel<<<dim3(gx, 2), 512, 0, stream>>>(h, Wb, z, N, ntiles);

    bhist_kernel<<<256, 256, 0, stream>>>(dst, counts, E, NB);
    bscan_kernel<<<1, 256, 0, stream>>>(counts, bases, cursor, NB);
    scatter1_kernel<<<(E + ECHUNK - 1) / ECHUNK, 1024, 0, stream>>>(src, dst, cursor, pairs, E, NB);
    sortb_kernel<<<NB, 256, 0, stream>>>(pairs, bases, rowptr, N, NB, E);

    int nblk = (N + 15) / 16;                   // 6250
    if (bf16agg)
        agg_kernel<1><<<nblk, 256, 0, stream>>>(z, pairs, rowptr, out, aggb, partials, 0, N);
    else
        agg_kernel<0><<<nblk, 256, 0, stream>>>(z, pairs, rowptr, out, aggb, partials, 0, N);

    fscale_kernel<<<1, 256, 0, stream>>>(partials, gamma, beta, ss, 1.0f / (float)N);
    int total8 = N * (NCH / 8);
    if (bf16agg)
        final_kernel<1><<<2048, 256, 0, stream>>>(h, ss, out, aggb, out, total8);
    else
        final_kernel<0><<<2048, 256, 0, stream>>>(h, ss, out, aggb, out, total8);
}

// Round 15
// 265.218 us; speedup vs baseline: 1.7569x; 1.0636x over previous
//
#include <hip/hip_runtime.h>
#include <hip/hip_bf16.h>

#define NCH 256     // H*OUT_DIM = 8*32
#define DIM 256     // IN_DIM
#define BN  64      // nodes per bucket
#define NBMAX 2048  // max buckets (LDS sizing); NB = ceil(N/64) = 1563
#define SEG 8       // NBMAX/256 (bscan, 256 threads)
#define SEG2 2      // NBMAX/1024 (scatter1, 1024 threads)
#define ECHUNK 8192 // edges per scatter block
#define SCAP 4096   // sortb LDS capacity (bucket mean ~1024, std ~32)
#define NPART 64    // stats partial rows

using f32x4  = __attribute__((ext_vector_type(4))) float;
using s16x8  = __attribute__((ext_vector_type(8))) short;
using u16x8  = __attribute__((ext_vector_type(8))) unsigned short;

__device__ __forceinline__ unsigned short f2bf(float x) {
    unsigned u = __float_as_uint(x);
    u += 0x7FFFu + ((u >> 16) & 1u);   // RNE
    return (unsigned short)(u >> 16);
}
__device__ __forceinline__ float bf2f(unsigned short b) {
    return __uint_as_float(((unsigned)b) << 16);
}

// exclusive prefix over the 256 threads' values
__device__ __forceinline__ int block_scan256_excl(int v, int* wtmp) {
    int lane = threadIdx.x & 63, wv = threadIdx.x >> 6;
    int x = v;
#pragma unroll
    for (int d = 1; d < 64; d <<= 1) {
        int t = __shfl_up(x, d);
        if (lane >= d) x += t;
    }
    if (lane == 63) wtmp[wv] = x;
    __syncthreads();
    int wbase = 0;
#pragma unroll
    for (int w = 0; w < 4; ++w) wbase += (w < wv) ? wtmp[w] : 0;
    __syncthreads();
    return wbase + x - v;
}

// exclusive prefix over 1024 threads' values (16 waves)
__device__ __forceinline__ int block_scan1024_excl(int v, int* wtmp) {
    int lane = threadIdx.x & 63, wv = threadIdx.x >> 6;
    int x = v;
#pragma unroll
    for (int d = 1; d < 64; d <<= 1) {
        int t = __shfl_up(x, d);
        if (lane >= d) x += t;
    }
    if (lane == 63) wtmp[wv] = x;
    __syncthreads();
    int wbase = 0;
#pragma unroll
    for (int w = 0; w < 16; ++w) wbase += (w < wv) ? wtmp[w] : 0;
    __syncthreads();
    return wbase + x - v;
}

// ---------- cast W (f32 [256][256]) to bf16 ----------
__global__ __launch_bounds__(256) void cast_w_kernel(const float* __restrict__ W,
                                                     unsigned short* __restrict__ Wb) {
    int i = blockIdx.x * 256 + threadIdx.x;
    Wb[i] = f2bf(W[i]);
}

// ---------- fused GEMM + bucket-histogram ----------
// blocks [0, 512): GEMM z[n][c] = sum_d h[n][d]*W[c][d] (x = bid&255 covers
// all 256 CUs -- R14's gx=196 left 60 CUs idle; by = bid>>8 selects col half).
// blocks [512, 768): dst bucket histogram (independent of gemm -> overlaps
// gemm's tail). LDS 64KB+8KB = 72KB -> 2 blocks/CU, same as before.
__global__ __launch_bounds__(512, 4) void gemm_bhist_kernel(const float* __restrict__ h,
                                                            const unsigned short* __restrict__ Wb,
                                                            unsigned short* __restrict__ z,
                                                            const int* __restrict__ dst,
                                                            int* __restrict__ counts,
                                                            int N, int ntiles, int E, int NB,
                                                            int gemmBlocks) {
    __shared__ __align__(16) unsigned short lds[32768];   // 64 KB: 128 cols x 256 k
    __shared__ int hcnt[NBMAX];                            // 8 KB (bhist branch)
    int bid = blockIdx.x;
    int tid = threadIdx.x;

    if (bid >= gemmBlocks) {
        // ---- bhist branch: 256 blocks x 512 threads ----
        int nbh = gridDim.x - gemmBlocks;
        int hb  = bid - gemmBlocks;
        for (int i = tid; i < NB; i += 512) hcnt[i] = 0;
        __syncthreads();
        for (int j = hb * 512 + tid; j < E; j += nbh * 512)
            atomicAdd(&hcnt[dst[j] >> 6], 1);
        __syncthreads();
        for (int i = tid; i < NB; i += 512)
            if (hcnt[i]) atomicAdd(&counts[i], hcnt[i]);
        return;
    }

    // ---- gemm branch ----
    int x  = bid & 255;
    int by = bid >> 8;

    const unsigned short* wsrc = Wb + (size_t)by * 32768;
    for (int it = 0; it < 8; ++it) {
        int c = it * 512 + tid;               // 16B chunk index, 4096 total
        int lin = c * 16;
        int dstb = lin ^ (((lin >> 9) & 7) << 4);
        *reinterpret_cast<u16x8*>((char*)lds + dstb) =
            *reinterpret_cast<const u16x8*>(wsrc + c * 8);
    }
    __syncthreads();   // LDS read-only from here; no barriers in tile loop

    int wv = tid >> 6, lane = tid & 63;
    int lrow = lane & 15;
    int lk   = (lane >> 4) * 8;

    int ldsoff[8];
#pragma unroll
    for (int kk = 0; kk < 8; ++kk)
        ldsoff[kk] = ((lrow * 512 + kk * 64 + lk * 2) ^ ((lrow & 7) << 4));

    for (int tile = x; tile < ntiles; tile += 256) {
        int r0 = tile * 128 + wv * 16;
        if (r0 >= N) continue;
        int row = r0 + lrow;

        float4 cur[16];
        if (row < N) {
            const float* ap = h + (size_t)row * DIM;
#pragma unroll
            for (int kk = 0; kk < 8; ++kk) {
                cur[2 * kk]     = *reinterpret_cast<const float4*>(ap + kk * 32 + lk);
                cur[2 * kk + 1] = *reinterpret_cast<const float4*>(ap + kk * 32 + lk + 4);
            }
        } else {
#pragma unroll
            for (int i = 0; i < 16; ++i) cur[i] = float4{0.f, 0.f, 0.f, 0.f};
        }

        f32x4 acc[8];
#pragma unroll
        for (int ct = 0; ct < 8; ++ct) acc[ct] = f32x4{0.f, 0.f, 0.f, 0.f};
#pragma unroll
        for (int kk = 0; kk < 8; ++kk) {
            union { s16x8 v; __hip_bfloat162 b2[4]; } u;
            float4 f0 = cur[2 * kk], f1 = cur[2 * kk + 1];
            u.b2[0] = __float22bfloat162_rn(float2{f0.x, f0.y});
            u.b2[1] = __float22bfloat162_rn(float2{f0.z, f0.w});
            u.b2[2] = __float22bfloat162_rn(float2{f1.x, f1.y});
            u.b2[3] = __float22bfloat162_rn(float2{f1.z, f1.w});
            s16x8 a = u.v;
#pragma unroll
            for (int ct = 0; ct < 8; ++ct) {
                s16x8 b = *reinterpret_cast<const s16x8*>(
                    (const char*)lds + (ldsoff[kk] + ct * 8192));
                acc[ct] = __builtin_amdgcn_mfma_f32_16x16x32_bf16(a, b, acc[ct], 0, 0, 0);
            }
        }
        int drow = (lane >> 4) * 4;
#pragma unroll
        for (int ct = 0; ct < 8; ++ct) {
#pragma unroll
            for (int r = 0; r < 4; ++r) {
                int orow = r0 + drow + r;
                if (orow < N)
                    z[(size_t)orow * NCH + by * 128 + ct * 16 + lrow] = f2bf(acc[ct][r]);
            }
        }
    }
}

// ---------- scan over NB buckets -> bases[0..NB], cursor copy ----------
__global__ __launch_bounds__(256) void bscan_kernel(const int* __restrict__ counts,
                                                    int* __restrict__ bases,
                                                    int* __restrict__ cursor, int NB) {
    __shared__ int wtmp[4];
    int tid = threadIdx.x;
    int i0 = tid * SEG;
    int tsum = 0;
#pragma unroll
    for (int k = 0; k < SEG; ++k) {
        int idx = i0 + k;
        if (idx < NB) tsum += counts[idx];
    }
    int run = block_scan256_excl(tsum, wtmp);
#pragma unroll
    for (int k = 0; k < SEG; ++k) {
        int idx = i0 + k;
        if (idx < NB) {
            bases[idx]  = run;
            cursor[idx] = run;
            run += counts[idx];
        } else if (idx == NB) {
            bases[NB] = run;
        }
    }
}

// ---------- scatter edges into bucket-grouped packed list ----------
// 1024 threads + sbkt O(1) write-out (R12-proven: 91us -> sub-cutoff).
// pack: src (17b) | local_dst (6b) << 17
__global__ __launch_bounds__(1024) void scatter1_kernel(const int* __restrict__ src,
                                                        const int* __restrict__ dst,
                                                        int* __restrict__ cursor,
                                                        unsigned* __restrict__ pairs,
                                                        int E, int NB) {
    __shared__ int cnt[NBMAX];      // then reused as local cursor
    __shared__ int excl0[NBMAX];
    __shared__ int gb[NBMAX];
    __shared__ unsigned staged[ECHUNK];
    __shared__ unsigned short sbkt[ECHUNK];
    __shared__ int wtmp[16];
    int tid = threadIdx.x;
    int base = blockIdx.x * ECHUNK;
    int n = min(ECHUNK, E - base);

    for (int i = tid; i < NB; i += 1024) cnt[i] = 0;
    __syncthreads();
    for (int j = tid; j < n; j += 1024)
        atomicAdd(&cnt[dst[base + j] >> 6], 1);
    __syncthreads();

    int i0 = tid * SEG2;
    int tsum = 0;
#pragma unroll
    for (int k = 0; k < SEG2; ++k) {
        int idx = i0 + k;
        if (idx < NB) tsum += cnt[idx];
    }
    int run = block_scan1024_excl(tsum, wtmp);
#pragma unroll
    for (int k = 0; k < SEG2; ++k) {
        int idx = i0 + k;
        if (idx < NB) {
            int c = cnt[idx];
            excl0[idx] = run;
            gb[idx] = c ? atomicAdd(&cursor[idx], c) : 0;
            run += c;
        }
    }
    __syncthreads();
    for (int i = tid; i < NB; i += 1024) cnt[i] = excl0[i];   // cnt -> local cursor
    __syncthreads();
    for (int j = tid; j < n; j += 1024) {
        int d = dst[base + j];
        int b = d >> 6;
        int slot = atomicAdd(&cnt[b], 1);
        staged[slot] = (unsigned)src[base + j] | ((unsigned)(d & 63) << 17);
        sbkt[slot]   = (unsigned short)b;
    }
    __syncthreads();
    // linear write-out: consecutive j -> consecutive positions within bucket runs
    for (int j = tid; j < n; j += 1024) {
        int b = sbkt[j];
        pairs[gb[b] + (j - excl0[b])] = staged[j];
    }
}

// ---------- in-bucket counting sort + per-node rowptr; pairs -> plain src ----------
__global__ __launch_bounds__(256) void sortb_kernel(unsigned* __restrict__ pairs,
                                                    const int* __restrict__ bases,
                                                    int* __restrict__ rowptr,
                                                    int N, int NB, int E) {
    __shared__ unsigned raw[SCAP];
    __shared__ unsigned srt[SCAP];
    __shared__ int cnt[BN];
    __shared__ int rp[BN + 1];
    __shared__ int cur[BN];
    int bkt = blockIdx.x, tid = threadIdx.x;
    int ebeg = bases[bkt];
    int ne = min(bases[bkt + 1] - ebeg, SCAP);

    if (tid < BN) cnt[tid] = 0;
    __syncthreads();
    for (int i = tid; i < ne; i += 256) {
        unsigned e = pairs[ebeg + i];
        raw[i] = e;
        atomicAdd(&cnt[(e >> 17) & 63], 1);
    }
    __syncthreads();
    if (tid < 64) {                 // wave 0: exclusive scan of cnt[0..63]
        int x = cnt[tid];
#pragma unroll
        for (int d = 1; d < 64; d <<= 1) {
            int t = __shfl_up(x, d);
            if (tid >= d) x += t;
        }
        rp[tid + 1] = x;
        if (tid == 0) rp[0] = 0;
    }
    __syncthreads();
    if (tid < BN) cur[tid] = rp[tid];
    int node = bkt * BN + tid;
    if (tid < BN && node < N) rowptr[node] = ebeg + rp[tid];
    if (bkt == NB - 1 && tid == 0) rowptr[N] = E;
    __syncthreads();
    for (int i = tid; i < ne; i += 256) {
        unsigned e = raw[i];
        int slot = atomicAdd(&cur[(e >> 17) & 63], 1);
        srt[slot] = e & 0x1FFFFu;
    }
    __syncthreads();
    for (int i = tid; i < ne; i += 256) pairs[ebeg + i] = srt[i];
}

// ---------- pull aggregation + register-level BN stats ----------
// 4 nodes per wave (16 per block); 32 lanes per row (16B/lane), 2 edges per
// pair-step, unroll 4 -> 4 outstanding 16B gathers per lane (proven best).
template <int BF16OUT>
__global__ __launch_bounds__(256) void agg_kernel(const unsigned short* __restrict__ z,
                                                  const unsigned* __restrict__ pairs,
                                                  const int* __restrict__ rowptr,
                                                  float* __restrict__ outf,
                                                  unsigned short* __restrict__ outb,
                                                  float* __restrict__ partials,
                                                  int node0, int N) {
    __shared__ float redu[4][32][17];   // 17: odd stride -> conflict-free
    int tid = threadIdx.x;
    int wv = tid >> 6, lane = tid & 63;
    int half = lane >> 5;          // which edge within the pair
    int l    = lane & 31;          // channel group: owns channels 8l..8l+7
    const unsigned short* zb = z + l * 8;

    float sum[8], sq[8];
#pragma unroll
    for (int j = 0; j < 8; ++j) { sum[j] = 0.f; sq[j] = 0.f; }

    for (int k = 0; k < 4; ++k) {
        int node = node0 + blockIdx.x * 16 + wv * 4 + k;
        if (node >= N) break;
        int beg = rowptr[node], end = rowptr[node + 1];

        float s[8];
#pragma unroll
        for (int j = 0; j < 8; ++j) s[j] = 0.f;

        int i = beg + half;
        for (; i + 6 < end; i += 8) {
            int n0 = pairs[i];
            int n1 = pairs[i + 2];
            int n2 = pairs[i + 4];
            int n3 = pairs[i + 6];
            u16x8 v0 = *reinterpret_cast<const u16x8*>(zb + (size_t)n0 * NCH);
            u16x8 v1 = *reinterpret_cast<const u16x8*>(zb + (size_t)n1 * NCH);
            u16x8 v2 = *reinterpret_cast<const u16x8*>(zb + (size_t)n2 * NCH);
            u16x8 v3 = *reinterpret_cast<const u16x8*>(zb + (size_t)n3 * NCH);
#pragma unroll
            for (int j = 0; j < 8; ++j)
                s[j] += (bf2f(v0[j]) + bf2f(v1[j])) + (bf2f(v2[j]) + bf2f(v3[j]));
        }
        for (; i < end; i += 2) {
            int n0 = pairs[i];
            u16x8 v0 = *reinterpret_cast<const u16x8*>(zb + (size_t)n0 * NCH);
#pragma unroll
            for (int j = 0; j < 8; ++j) s[j] += bf2f(v0[j]);
        }
#pragma unroll
        for (int j = 0; j < 8; ++j) s[j] += __shfl_xor(s[j], 32);

        if (half == 0) {
            if (BF16OUT) {
                u16x8 ob;
#pragma unroll
                for (int j = 0; j < 8; ++j) ob[j] = f2bf(s[j]);
                *reinterpret_cast<u16x8*>(outb + (size_t)node * NCH + l * 8) = ob;
            } else {
                float4 o0; o0.x = s[0]; o0.y = s[1]; o0.z = s[2]; o0.w = s[3];
                float4 o1; o1.x = s[4]; o1.y = s[5]; o1.z = s[6]; o1.w = s[7];
                float* p = outf + (size_t)node * NCH + l * 8;
                *reinterpret_cast<float4*>(p)     = o0;
                *reinterpret_cast<float4*>(p + 4) = o1;
            }
#pragma unroll
            for (int j = 0; j < 8; ++j) { sum[j] += s[j]; sq[j] += s[j] * s[j]; }
        }
    }

    if (half == 0) {
#pragma unroll
        for (int j = 0; j < 8; ++j) {
            redu[wv][l][j]     = sum[j];
            redu[wv][l][j + 8] = sq[j];
        }
    }
    __syncthreads();
    {
        int c = tid;                 // channel 0..255
        int lc = c >> 3, jc = c & 7;
        float v = 0.f, q = 0.f;
#pragma unroll
        for (int w = 0; w < 4; ++w) {
            v += redu[w][lc][jc];
            q += redu[w][lc][jc + 8];
        }
        float* prow = partials + (size_t)(blockIdx.x & (NPART - 1)) * 512;
        atomicAdd(&prow[c], v);
        atomicAdd(&prow[256 + c], q);
    }
}

// ---------- finalize scale/shift from partials ----------
__global__ __launch_bounds__(256) void fscale_kernel(const float* __restrict__ partials,
                                                     const float* __restrict__ gamma,
                                                     const float* __restrict__ beta,
                                                     float* __restrict__ ss, float invN) {
    int c = threadIdx.x;
    float sum = 0.f, sq = 0.f;
    for (int r = 0; r < NPART; ++r) {
        sum += partials[(size_t)r * 512 + c];
        sq  += partials[(size_t)r * 512 + 256 + c];
    }
    float mean = sum * invN;
    float var  = sq * invN - mean * mean;
    float rs   = rsqrtf(var + 1e-5f);
    float sc   = gamma[c] * rs;
    ss[c]       = sc;
    ss[256 + c] = beta[c] - mean * sc;
}

// ---------- final: out = h + elu(agg*scale + shift) ----------
// scale/shift hoisted to registers; native exp2 ELU (R11-proven: 105->~35us).
template <int BF16IN>
__global__ __launch_bounds__(256) void final_kernel(const float* __restrict__ h,
                                                    const float* __restrict__ ss,
                                                    const float* __restrict__ aggf,
                                                    const unsigned short* __restrict__ aggb,
                                                    float* __restrict__ out, int total8) {
    int tid0 = blockIdx.x * 256 + threadIdx.x;
    int stride = gridDim.x * 256;         // multiple of 32 -> (i & 31) invariant
    int cb = (tid0 & 31) * 8;
    float sc[8], sh[8];
#pragma unroll
    for (int j = 0; j < 8; ++j) {
        sc[j] = ss[cb + j];
        sh[j] = ss[256 + cb + j];
    }
    const float LOG2E = 1.44269504088896f;
    for (int i = tid0; i < total8; i += stride) {
        float a[8];
        if (BF16IN) {
            u16x8 v = *reinterpret_cast<const u16x8*>(aggb + (size_t)i * 8);
#pragma unroll
            for (int j = 0; j < 8; ++j) a[j] = bf2f(v[j]);
        } else {
            float4 x = *reinterpret_cast<const float4*>(aggf + (size_t)i * 8);
            float4 y = *reinterpret_cast<const float4*>(aggf + (size_t)i * 8 + 4);
            a[0] = x.x; a[1] = x.y; a[2] = x.z; a[3] = x.w;
            a[4] = y.x; a[5] = y.y; a[6] = y.z; a[7] = y.w;
        }
        float4 h0 = *reinterpret_cast<const float4*>(h + (size_t)i * 8);
        float4 h1 = *reinterpret_cast<const float4*>(h + (size_t)i * 8 + 4);
        float r[8];
#pragma unroll
        for (int j = 0; j < 8; ++j) {
            float y = a[j] * sc[j] + sh[j];
            float e = __builtin_amdgcn_exp2f(y * LOG2E) - 1.0f;
            r[j] = (y > 0.f) ? y : e;
        }
        float4 o0, o1;
        o0.x = h0.x + r[0]; o0.y = h0.y + r[1]; o0.z = h0.z + r[2]; o0.w = h0.w + r[3];
        o1.x = h1.x + r[4]; o1.y = h1.y + r[5]; o1.z = h1.z + r[6]; o1.w = h1.w + r[7];
        *reinterpret_cast<float4*>(out + (size_t)i * 8)     = o0;
        *reinterpret_cast<float4*>(out + (size_t)i * 8 + 4) = o1;
    }
}

extern "C" void kernel_launch(void* const* d_in, const int* in_sizes, int n_in,
                              void* d_out, int out_size, void* d_ws, size_t ws_size,
                              hipStream_t stream) {
    const float* h     = (const float*)d_in[0];
    const float* W     = (const float*)d_in[1];
    const float* gamma = (const float*)d_in[2];
    const float* beta  = (const float*)d_in[3];
    const int*   src   = (const int*)d_in[4];
    const int*   dst   = (const int*)d_in[5];
    int N = in_sizes[0] / DIM;   // 100000
    int E = in_sizes[4];         // 1600000
    int NB = (N + BN - 1) / BN;  // 1563
    float* out = (float*)d_out;

    char* ws = (char*)d_ws;
    size_t off = 0;
    auto alloc = [&](size_t bytes) {
        size_t o = off;
        off += (bytes + 255) & ~(size_t)255;
        return o;
    };
    unsigned short* z        = (unsigned short*)(ws + alloc((size_t)N * NCH * 2));
    unsigned short* Wb       = (unsigned short*)(ws + alloc((size_t)NCH * DIM * 2));
    size_t zero_begin        = off;
    int*            counts   = (int*)(ws + alloc((size_t)NB * 4));
    float*          partials = (float*)(ws + alloc((size_t)NPART * 512 * 4));
    size_t zero_end          = off;
    int*            cursor   = (int*)(ws + alloc((size_t)NB * 4));
    int*            bases    = (int*)(ws + alloc((size_t)(NB + 1) * 4));
    int*            rowptr   = (int*)(ws + alloc((size_t)(N + 1) * 4));
    float*          ss       = (float*)(ws + alloc(512 * 4));
    unsigned*       pairs    = (unsigned*)(ws + alloc((size_t)E * 4));
    // optional bf16 agg buffer (51 MB) -- only if workspace allows
    size_t aggb_off          = alloc((size_t)N * NCH * 2);
    bool bf16agg = (off <= ws_size);
    unsigned short* aggb     = (unsigned short*)(ws + aggb_off);

    hipMemsetAsync(ws + zero_begin, 0, zero_end - zero_begin, stream);

    cast_w_kernel<<<(NCH * DIM) / 256, 256, 0, stream>>>(W, Wb);

    int ntiles = (N + 127) / 128;               // 782
    int gemmBlocks = 512;                       // 256 x-tiles x 2 col-halves
    int bhistBlocks = 256;
    gemm_bhist_kernel<<<gemmBlocks + bhistBlocks, 512, 0, stream>>>(
        h, Wb, z, dst, counts, N, ntiles, E, NB, gemmBlocks);

    bscan_kernel<<<1, 256, 0, stream>>>(counts, bases, cursor, NB);
    scatter1_kernel<<<(E + ECHUNK - 1) / ECHUNK, 1024, 0, stream>>>(src, dst, cursor, pairs, E, NB);
    sortb_kernel<<<NB, 256, 0, stream>>>(pairs, bases, rowptr, N, NB, E);

    int nblk = (N + 15) / 16;                   // 6250
    if (bf16agg)
        agg_kernel<1><<<nblk, 256, 0, stream>>>(z, pairs, rowptr, out, aggb, partials, 0, N);
    else
        agg_kernel<0><<<nblk, 256, 0, stream>>>(z, pairs, rowptr, out, aggb, partials, 0, N);

    fscale_kernel<<<1, 256, 0, stream>>>(partials, gamma, beta, ss, 1.0f / (float)N);
    int total8 = N * (NCH / 8);
    if (bf16agg)
        final_kernel<1><<<2048, 256, 0, stream>>>(h, ss, out, aggb, out, total8);
    else
        final_kernel<0><<<2048, 256, 0, stream>>>(h, ss, out, aggb, out, total8);
}